// Round 14
// baseline (1054.573 us; speedup 1.0000x reference)
//
#include <hip/hip_runtime.h>
#include <math.h>

typedef _Float16 f16;
typedef _Float16 f16x8 __attribute__((ext_vector_type(8)));
typedef float    f32x4 __attribute__((ext_vector_type(4)));

#define MFMA16(A, B, C) __builtin_amdgcn_mfma_f32_16x16x32_f16((A), (B), (C), 0, 0, 0)
#define LOG2E 1.44269504088896f

// Weights/biases pre-scaled by -log2e (sigmoid) or -2*log2e (g gate):
// sigma(z) = rcp(1 + 2^acc) with a bare v_exp_f32.
__device__ __forceinline__ float sig2(float a) {
    return __builtin_amdgcn_rcpf(1.0f + __builtin_amdgcn_exp2f(a));
}
__device__ __forceinline__ float tanh2(float c) {
    return fmaf(2.0f, sig2(c * (-2.0f * LOG2E)), -1.0f);
}
__device__ __forceinline__ float xor32(float v) {
    return __shfl_xor(v, 32, 64);
}

// Quad-pair-split LSTM cell activation: quads 0,1 evaluate sigma(i),sigma(f);
// quads 2,3 evaluate tanh(g),sigma(o); one xor-32 exchange merges them.
// Result h and updated c are valid on quads 0,1 only (6 transcendentals/lane
// instead of 10). Uniform (non-divergent) code.
__device__ __forceinline__ float cell_act(const float v[4], float& c, int quad) {
    float va = (quad < 2) ? v[0] : v[2];
    float vb = (quad < 2) ? v[1] : v[3];
    float sa = sig2(va);
    float sb = sig2(vb);
    sa = (quad < 2) ? sa : fmaf(2.0f, sa, -1.0f);  // upper quads: tanh(g)
    float xa = xor32(sa);   // quads<2 receive tanh(g)
    float xb = xor32(sb);   // quads<2 receive sigma(o)
    c = fmaf(sb, c, sa * xa);
    return xb * tanh2(c);
}

__device__ __forceinline__ f16x8 ldfrag(const float* __restrict__ W, int n, int k0, float s) {
    const float* p = W + (size_t)n * 64 + k0;
    f16x8 r;
#pragma unroll
    for (int j = 0; j < 8; j++) r[j] = (f16)(s * p[j]);
    return r;
}

// One block per BATCH PAIR; 512 threads = 8 waves: A (wv0-3) = enc L1 / dec1,
// B (wv4-7) = enc L2 / dec2 + batched MFMA FC (wv6-7).
// Encoder: M=2 rows (both batches), lag-pipelined L1/L2, 1 barrier/tick.
// Decoder: BATCH-SKEWED, M=1 per group: phase p: A does dec1(b=p&1, t=p>>1)
// while B does dec2(1-b, previous half-step) -> both groups active EVERY
// phase (2 waves/SIMD latency hiding). Buffer slots disjoint by batch.
__global__ __launch_bounds__(512, 2)
void seq2seq_kernel(const float* __restrict__ src, const float* __restrict__ trg,
                    const float* __restrict__ e1ih, const float* __restrict__ e1hh,
                    const float* __restrict__ e1b,
                    const float* __restrict__ e2ih, const float* __restrict__ e2hh,
                    const float* __restrict__ e2b,
                    const float* __restrict__ d1ih, const float* __restrict__ d1hh,
                    const float* __restrict__ d1b,
                    const float* __restrict__ d2ih, const float* __restrict__ d2hh,
                    const float* __restrict__ d2b,
                    const float* __restrict__ fcW, const float* __restrict__ fcb,
                    float* __restrict__ out)
{
    const int bp   = blockIdx.x;
    const int tid  = threadIdx.x;
    const int wv   = tid >> 6;               // 0..7
    const bool isB = (wv >= 4);
    const int wvg  = wv & 3;
    const int lane = tid & 63;
    const int quad = lane >> 4;
    const int c15  = lane & 15;
    const int u16  = wvg * 16 + c15;
    const int qb   = quad & 1;               // encoder: batch of this lane
    const int ab   = c15 & 1;                // encoder: batch of this A-row

    __shared__ __align__(16) float xst[1024][8];   // [t][bat*4+c] src, 32 KB
    __shared__ __align__(16) float tst[512][8];    // trg, 16 KB
    __shared__ __align__(16) f16 h1l[2][2][64];    // encoder [buf][bat][u]
    __shared__ __align__(16) f16 h2l[2][2][64];
    __shared__ __align__(16) f16 hDl[2][64];       // decoder hD state [bat][u]
    __shared__ __align__(16) f16 h1dl[2][64];      // decoder h1d [bat][u]
    __shared__ float c1buf[2][64];                 // dec1 cell out (A -> B)
    __shared__ float c2buf[2][64];                 // dec2 cell out (B -> A)
    __shared__ __align__(16) f16 ring[2][16][72];  // [bat][step&15][u] hD history

    // ---- one-time staging of src/trg into LDS ----
    {
        const float* s0 = src + (size_t)(2 * bp) * 3072;
        const float* s1 = s0 + 3072;
        for (int i = tid; i < 3072; i += 512) {
            int t = i / 3, c = i - 3 * t;
            xst[t][c]     = s0[i];
            xst[t][4 + c] = s1[i];
        }
        const float* t0p = trg + (size_t)(2 * bp) * 1536;
        const float* t1p = t0p + 1536;
        for (int i = tid; i < 1536; i += 512) {
            int t = i / 3, c = i - 3 * t;
            tst[t][c]     = t0p[i];
            tst[t][4 + c] = t1p[i];
        }
    }

    // ---- group-specialized encoder weights ----
    f16x8 E1hh[4][2];                        // A only
    f16x8 E2ih[4][2], E2hh[4][2];            // B only
    float xw[4][3], bias1[4];
    f32x4 bs2[4];                            // B: bias2 splat (MFMA C-init)
    if (!isB) {
#pragma unroll
        for (int g = 0; g < 4; g++) {
            const float s = (g == 2) ? (-2.0f * LOG2E) : (-LOG2E);
            const int n = g * 64 + u16;
#pragma unroll
            for (int c = 0; c < 2; c++)
                E1hh[g][c] = ldfrag(e1hh, n, c * 32 + quad * 8, s);
            xw[g][0] = s * e1ih[n * 3 + 0];
            xw[g][1] = s * e1ih[n * 3 + 1];
            xw[g][2] = s * e1ih[n * 3 + 2];
            bias1[g] = s * e1b[n];
        }
    } else {
#pragma unroll
        for (int g = 0; g < 4; g++) {
            const float s = (g == 2) ? (-2.0f * LOG2E) : (-LOG2E);
            const int n = g * 64 + u16;
#pragma unroll
            for (int c = 0; c < 2; c++) {
                E2ih[g][c] = ldfrag(e2ih, n, c * 32 + quad * 8, s);
                E2hh[g][c] = ldfrag(e2hh, n, c * 32 + quad * 8, s);
            }
            float bv = s * e2b[n];
            bs2[g] = (f32x4){bv, bv, bv, bv};
        }
    }

    float c1 = 0.f, c2 = 0.f;                // c1 in A (quads 0,1), c2 in B
    float h2last = 0.f;                      // B: final h2 for handoff
    if (tid < 256) {
        (&h1l[0][0][0])[tid] = (f16)0.f;
        (&h2l[0][0][0])[tid] = (f16)0.f;
    }
    __syncthreads();

    const f32x4 z4 = {0.f, 0.f, 0.f, 0.f};

    // x prefetch registers (A only)
    f32x4 xq = z4, xnq = z4;
    if (!isB) xq = *(const f32x4*)&xst[0][qb * 4];

    // ---------------- encoder: 1025 pipelined ticks, 1 barrier each --------
#pragma unroll 1
    for (int tau = 0; tau <= 1024; tau++) {
        const int w = tau & 1;
        if (!isB) {
            if (tau < 1024) {                // L1: h1(tau) = f(h1(tau-1), x(tau))
                const f16* h1p = h1l[w ^ 1][ab];
                f16x8 a0 = *(const f16x8*)(h1p + quad * 8);
                f16x8 a1 = *(const f16x8*)(h1p + 32 + quad * 8);
                float xt[4];
#pragma unroll
                for (int g = 0; g < 4; g++)
                    xt[g] = fmaf(xw[g][0], xq.x,
                            fmaf(xw[g][1], xq.y, fmaf(xw[g][2], xq.z, bias1[g])));
                f32x4 acc[4];
#pragma unroll
                for (int g = 0; g < 4; g++)
                    acc[g] = MFMA16(a1, E1hh[g][1], MFMA16(a0, E1hh[g][0], z4));
                float v[4];
#pragma unroll
                for (int g = 0; g < 4; g++)
                    v[g] = (qb ? acc[g][1] : acc[g][0]) + xt[g];
                float h1n = cell_act(v, c1, quad);
                if (quad < 2) h1l[w][quad][u16] = (f16)h1n;
                const int tn = (tau + 1 < 1024) ? tau + 1 : 1023;
                xnq = *(const f32x4*)&xst[tn][qb * 4];
            }
        } else {
            if (tau > 0) {                   // L2: h2(tau-1) = f(h1(tau-1), h2(tau-2))
                const f16* h1p = h1l[w ^ 1][ab];
                const f16* h2p = h2l[w ^ 1][ab];
                f16x8 a0 = *(const f16x8*)(h1p + quad * 8);
                f16x8 a1 = *(const f16x8*)(h1p + 32 + quad * 8);
                f16x8 b0 = *(const f16x8*)(h2p + quad * 8);
                f16x8 b1 = *(const f16x8*)(h2p + 32 + quad * 8);
                f32x4 accA[4], accB[4];
#pragma unroll
                for (int g = 0; g < 4; g++) {
                    accA[g] = MFMA16(a1, E2ih[g][1], MFMA16(a0, E2ih[g][0], bs2[g]));
                    accB[g] = MFMA16(b1, E2hh[g][1], MFMA16(b0, E2hh[g][0], z4));
                }
                float v[4];
#pragma unroll
                for (int g = 0; g < 4; g++)
                    v[g] = (qb ? accA[g][1] : accA[g][0]) +
                           (qb ? accB[g][1] : accB[g][0]);
                float h2n = cell_act(v, c2, quad);
                h2last = h2n;
                if (quad < 2) h2l[w][quad][u16] = (f16)h2n;
            }
        }
        __syncthreads();
        if (!isB) xq = xnq;
    }
    // h2(1023) in h2last (B quads 0,1); c2 in B registers (quads 0,1)

    // ---------------- decoder weights (group-specialized) -------------------
    f16x8 D1hh[4][2];                        // A
    f16x8 W2s[4][2];                         // B
    float dxw[4][3], db1[4];
    f32x4 db2s[4];                           // B: dec2 bias splat (C-init)
    if (!isB) {
#pragma unroll
        for (int g = 0; g < 4; g++) {
            const float s = (g == 2) ? (-2.0f * LOG2E) : (-LOG2E);
            const int n = g * 64 + u16;
#pragma unroll
            for (int c = 0; c < 2; c++)
                D1hh[g][c] = ldfrag(d1hh, n, c * 32 + quad * 8, s);
            dxw[g][0] = s * d1ih[n * 3 + 0];
            dxw[g][1] = s * d1ih[n * 3 + 1];
            dxw[g][2] = s * d1ih[n * 3 + 2];
            db1[g] = s * d1b[n];
        }
    } else {
#pragma unroll
        for (int g = 0; g < 4; g++) {
            const float s = (g == 2) ? (-2.0f * LOG2E) : (-LOG2E);
            const int n = g * 64 + u16;
#pragma unroll
            for (int c = 0; c < 2; c++) {
                const int k0 = c * 32 + quad * 8;
                const float* pa = d2ih + (size_t)n * 64 + k0;
                const float* pb = d2hh + (size_t)n * 64 + k0;
                f16x8 r;
#pragma unroll
                for (int j = 0; j < 8; j++) r[j] = (f16)(s * (pa[j] + pb[j]));
                W2s[g][c] = r;
            }
            float bv = s * d2b[n];
            db2s[g] = (f32x4){bv, bv, bv, bv};
        }
        // handoff: decoder initial state hD = h2(1023), c = c2 (quads 0,1 = batch)
        if (quad < 2) {
            hDl[quad][u16]  = (f16)h2last;
            c2buf[quad][u16] = c2;
        }
    }
    // FC: register B-fragments of fcW^T (waves 6-7); B[k][n]=fcW[n][k], n=c15
    f16x8 FW0 = {}, FW1 = {};
    float fb = 0.f;
    if (wv >= 6 && c15 < 3) {
#pragma unroll
        for (int j = 0; j < 8; j++) {
            FW0[j] = (f16)fcW[c15 * 64 + quad * 8 + j];
            FW1[j] = (f16)fcW[c15 * 64 + 32 + quad * 8 + j];
        }
        fb = fcb[c15];
    }
    __syncthreads();

    // trg prefetch (A only): phase p -> batch p&1, step p>>1
    f32x4 tq = z4, tnq = z4;
    if (!isB) tq = *(const f32x4*)&tst[0][0];

    // ------------- decoder: 1023 batch-skewed phases, 1 barrier each --------
    // phase p: A: dec1(b=p&1, t=p>>1)  [p<1022]
    //          B: dec2(1-b, t'=(p-1)>>1) [p>0]
#pragma unroll 1
    for (int p = 0; p < 1023; p++) {
        const int b = p & 1;
        if (!isB) {
            if (p < 1022) {
                const f16* hp = hDl[b];
                f16x8 a0 = *(const f16x8*)(hp + quad * 8);
                f16x8 a1 = *(const f16x8*)(hp + 32 + quad * 8);
                float cdin = c2buf[b][u16];
                float xt[4];
#pragma unroll
                for (int g = 0; g < 4; g++)
                    xt[g] = fmaf(dxw[g][0], tq.x,
                            fmaf(dxw[g][1], tq.y, fmaf(dxw[g][2], tq.z, db1[g])));
                f32x4 acc[4];
#pragma unroll
                for (int g = 0; g < 4; g++)
                    acc[g] = MFMA16(a1, D1hh[g][1], MFMA16(a0, D1hh[g][0], z4));
                float v[4];
#pragma unroll
                for (int g = 0; g < 4; g++)
                    v[g] = acc[g][0] + xt[g];          // M=1: row 0 everywhere
                float cc = cdin;
                float h1d = cell_act(v, cc, quad);
                if (quad == 0) {
                    h1dl[b][u16]  = (f16)h1d;
                    c1buf[b][u16] = cc;
                }
                // prefetch next phase's x (batch (p+1)&1, step (p+1)>>1)
                const int pn = (p + 1 < 1022) ? p + 1 : p;
                tnq = *(const f32x4*)&tst[pn >> 1][(pn & 1) * 4];
            }
        } else {
            if (p > 0) {
                const int bb = 1 - b;
                const int tb = (p - 1) >> 1;
                const f16* np = h1dl[bb];
                f16x8 m0 = *(const f16x8*)(np + quad * 8);
                f16x8 m1 = *(const f16x8*)(np + 32 + quad * 8);
                float c1in = c1buf[bb][u16];
                f32x4 acc[4];
#pragma unroll
                for (int g = 0; g < 4; g++)
                    acc[g] = MFMA16(m1, W2s[g][1], MFMA16(m0, W2s[g][0], db2s[g]));
                float v[4];
#pragma unroll
                for (int g = 0; g < 4; g++)
                    v[g] = acc[g][0];
                float cc = c1in;
                float hh = cell_act(v, cc, quad);
                if (quad == 0) {
                    f16 hf = (f16)hh;
                    hDl[bb][u16]  = hf;
                    c2buf[bb][u16] = cc;
                    ring[bb][tb & 15][u16] = hf;
                }
            }
            // batched FC (2 MFMAs per 32 phases per wave), steps t-16..t-1
            if (wv == 6 && (p & 31) == 0 && p >= 32 && p <= 992) {
                const int t = p >> 1;                  // multiple of 16
                const f16* rp = &ring[0][0][0];
                f16x8 fa0 = *(const f16x8*)(rp + c15 * 72 + quad * 8);
                f16x8 fa1 = *(const f16x8*)(rp + c15 * 72 + 32 + quad * 8);
                f32x4 facc = MFMA16(fa1, FW1, MFMA16(fa0, FW0, z4));
                if (c15 < 3) {
                    float* ob = out + (((size_t)(2 * bp) * 512 + (t - 15)) * 3) + c15;
#pragma unroll
                    for (int rg = 0; rg < 4; rg++)
                        ob[(quad * 4 + rg) * 3] = facc[rg] + fb;
                }
            }
            if (wv == 7 && (p & 31) == 1 && p >= 33 && p <= 993) {
                const int t = p >> 1;                  // multiple of 16
                const f16* rp = &ring[1][0][0];
                f16x8 fa0 = *(const f16x8*)(rp + c15 * 72 + quad * 8);
                f16x8 fa1 = *(const f16x8*)(rp + c15 * 72 + 32 + quad * 8);
                f32x4 facc = MFMA16(fa1, FW1, MFMA16(fa0, FW0, z4));
                if (c15 < 3) {
                    float* ob = out + (((size_t)(2 * bp + 1) * 512 + (t - 15)) * 3) + c15;
#pragma unroll
                    for (int rg = 0; rg < 4; rg++)
                        ob[(quad * 4 + rg) * 3] = facc[rg] + fb;
                }
            }
        }
        __syncthreads();
        if (!isB) tq = tnq;
    }

    // drain: FC for steps 496..510 (ring slots 0..14) -> out rows 497..511
    if (wv >= 6) {
        const int bsel = wv - 6;
        const f16* rp = &ring[bsel][0][0];
        f16x8 fa0 = *(const f16x8*)(rp + c15 * 72 + quad * 8);
        f16x8 fa1 = *(const f16x8*)(rp + c15 * 72 + 32 + quad * 8);
        f32x4 facc = MFMA16(fa1, FW1, MFMA16(fa0, FW0, z4));
        if (c15 < 3) {
            float* ob = out + (((size_t)(2 * bp + bsel) * 512 + 497) * 3) + c15;
#pragma unroll
            for (int rg = 0; rg < 4; rg++) {
                int step = quad * 4 + rg;
                if (step < 15) ob[step * 3] = facc[rg] + fb;
            }
        }
    }
}

extern "C" void kernel_launch(void* const* d_in, const int* in_sizes, int n_in,
                              void* d_out, int out_size, void* d_ws, size_t ws_size,
                              hipStream_t stream)
{
    const float* src   = (const float*)d_in[0];
    const float* trg   = (const float*)d_in[1];
    const float* e1ih  = (const float*)d_in[2];
    const float* e1hh  = (const float*)d_in[3];
    const float* e1b   = (const float*)d_in[4];
    const float* e2ih  = (const float*)d_in[5];
    const float* e2hh  = (const float*)d_in[6];
    const float* e2b   = (const float*)d_in[7];
    const float* dd1ih = (const float*)d_in[8];
    const float* dd1hh = (const float*)d_in[9];
    const float* dd1b  = (const float*)d_in[10];
    const float* dd2ih = (const float*)d_in[11];
    const float* dd2hh = (const float*)d_in[12];
    const float* dd2b  = (const float*)d_in[13];
    const float* fcW   = (const float*)d_in[14];
    const float* fcb   = (const float*)d_in[15];
    float* out = (float*)d_out;

    // outputs[:, 0, :] stays 0; decoder fills t >= 1
    hipMemsetAsync(d_out, 0, (size_t)out_size * sizeof(float), stream);

    seq2seq_kernel<<<256, 512, 0, stream>>>(src, trg,
                                            e1ih, e1hh, e1b, e2ih, e2hh, e2b,
                                            dd1ih, dd1hh, dd1b, dd2ih, dd2hh, dd2b,
                                            fcW, fcb, out);
}

// Round 15
// 930.987 us; speedup vs baseline: 1.1327x; 1.1327x over previous
//
#include <hip/hip_runtime.h>
#include <math.h>

typedef _Float16 f16;
typedef _Float16 f16x8 __attribute__((ext_vector_type(8)));
typedef float    f32x4 __attribute__((ext_vector_type(4)));

#define MFMA16(A, B, C) __builtin_amdgcn_mfma_f32_16x16x32_f16((A), (B), (C), 0, 0, 0)
#define LOG2E 1.44269504088896f

// Weights/biases pre-scaled by -log2e (sigmoid) or -2*log2e (g gate):
// sigma(z) = rcp(1 + 2^acc) with a bare v_exp_f32.
__device__ __forceinline__ float sig2(float a) {
    return __builtin_amdgcn_rcpf(1.0f + __builtin_amdgcn_exp2f(a));
}
__device__ __forceinline__ float tanh2(float c) {
    return fmaf(2.0f, sig2(c * (-2.0f * LOG2E)), -1.0f);
}

__device__ __forceinline__ f16x8 ldfrag(const float* __restrict__ W, int n, int k0, float s) {
    const float* p = W + (size_t)n * 64 + k0;
    f16x8 r;
#pragma unroll
    for (int j = 0; j < 8; j++) r[j] = (f16)(s * p[j]);
    return r;
}

// One block per BATCH PAIR; 512 threads = 8 waves.
// ENCODER (r11 structure): A (wv0-3) = L1, B (wv4-7) = L2, lag-pipelined,
// M=2 rows (batch = row&1 -> C reg0=batch0, reg1=batch1), 1 barrier/tick.
// DECODER (new): ALL 8 waves redundantly compute dec1 then dec2 (groups are
// identical copies) -> 2 waves/SIMD active every phase AND the cell state
// c1/c2 stays in each lane's registers (no LDS round-trip for c). Only h
// crosses waves through LDS. FC head: ring + 2 MFMAs on waves 6-7 / 16 steps.
__global__ __launch_bounds__(512, 2)
void seq2seq_kernel(const float* __restrict__ src, const float* __restrict__ trg,
                    const float* __restrict__ e1ih, const float* __restrict__ e1hh,
                    const float* __restrict__ e1b,
                    const float* __restrict__ e2ih, const float* __restrict__ e2hh,
                    const float* __restrict__ e2b,
                    const float* __restrict__ d1ih, const float* __restrict__ d1hh,
                    const float* __restrict__ d1b,
                    const float* __restrict__ d2ih, const float* __restrict__ d2hh,
                    const float* __restrict__ d2b,
                    const float* __restrict__ fcW, const float* __restrict__ fcb,
                    float* __restrict__ out)
{
    const int bp   = blockIdx.x;
    const int tid  = threadIdx.x;
    const int wv   = tid >> 6;               // 0..7
    const bool isB = (wv >= 4);
    const int wvg  = wv & 3;
    const int lane = tid & 63;
    const int quad = lane >> 4;
    const int c15  = lane & 15;
    const int u16  = wvg * 16 + c15;
    const int qb   = quad & 1;               // batch this lane's activations
    const int ab   = c15 & 1;                // batch this lane's A-row feeds

    __shared__ __align__(16) float xst[1024][8];   // [t][bat*4+c] src, 32 KB
    __shared__ __align__(16) float tst[512][8];    // trg, 16 KB
    __shared__ __align__(16) f16 h1l[2][2][64];    // [buf][bat][u]
    __shared__ __align__(16) f16 h2l[2][2][64];
    __shared__ float c2seed[2][64];                // encoder c2 -> all waves, once
    __shared__ __align__(16) f16 ring[2][16][72];  // [bat][step&15][u] hD history

    // ---- one-time staging of src/trg into LDS ----
    {
        const float* s0 = src + (size_t)(2 * bp) * 3072;
        const float* s1 = s0 + 3072;
        for (int i = tid; i < 3072; i += 512) {
            int t = i / 3, c = i - 3 * t;
            xst[t][c]     = s0[i];
            xst[t][4 + c] = s1[i];
        }
        const float* t0p = trg + (size_t)(2 * bp) * 1536;
        const float* t1p = t0p + 1536;
        for (int i = tid; i < 1536; i += 512) {
            int t = i / 3, c = i - 3 * t;
            tst[t][c]     = t0p[i];
            tst[t][4 + c] = t1p[i];
        }
    }

    // ---- group-specialized encoder weights ----
    f16x8 E1hh[4][2];                        // A only
    f16x8 E2ih[4][2], E2hh[4][2];            // B only
    float xw[4][3], bias1[4];
    f32x4 bs2[4];                            // B: bias2 splat (MFMA C-init)
    if (!isB) {
#pragma unroll
        for (int g = 0; g < 4; g++) {
            const float s = (g == 2) ? (-2.0f * LOG2E) : (-LOG2E);
            const int n = g * 64 + u16;
#pragma unroll
            for (int c = 0; c < 2; c++)
                E1hh[g][c] = ldfrag(e1hh, n, c * 32 + quad * 8, s);
            xw[g][0] = s * e1ih[n * 3 + 0];
            xw[g][1] = s * e1ih[n * 3 + 1];
            xw[g][2] = s * e1ih[n * 3 + 2];
            bias1[g] = s * e1b[n];
        }
    } else {
#pragma unroll
        for (int g = 0; g < 4; g++) {
            const float s = (g == 2) ? (-2.0f * LOG2E) : (-LOG2E);
            const int n = g * 64 + u16;
#pragma unroll
            for (int c = 0; c < 2; c++) {
                E2ih[g][c] = ldfrag(e2ih, n, c * 32 + quad * 8, s);
                E2hh[g][c] = ldfrag(e2hh, n, c * 32 + quad * 8, s);
            }
            float bv = s * e2b[n];
            bs2[g] = (f32x4){bv, bv, bv, bv};
        }
    }

    float c1 = 0.f, c2 = 0.f;                // c1 lives in A, c2 in B (encoder)
    if (tid < 256) {
        (&h1l[0][0][0])[tid] = (f16)0.f;
        (&h2l[0][0][0])[tid] = (f16)0.f;
    }
    __syncthreads();

    const f32x4 z4 = {0.f, 0.f, 0.f, 0.f};

    // x prefetch registers (A only)
    f32x4 xq = z4, xnq = z4;
    if (!isB) xq = *(const f32x4*)&xst[0][qb * 4];

    // ---------------- encoder: 1025 pipelined ticks, 1 barrier each --------
#pragma unroll 1
    for (int tau = 0; tau <= 1024; tau++) {
        const int w = tau & 1;
        if (!isB) {
            if (tau < 1024) {                // L1: h1(tau) = f(h1(tau-1), x(tau))
                const f16* h1p = h1l[w ^ 1][ab];
                f16x8 a0 = *(const f16x8*)(h1p + quad * 8);
                f16x8 a1 = *(const f16x8*)(h1p + 32 + quad * 8);
                float xt[4];
#pragma unroll
                for (int g = 0; g < 4; g++)
                    xt[g] = fmaf(xw[g][0], xq.x,
                            fmaf(xw[g][1], xq.y, fmaf(xw[g][2], xq.z, bias1[g])));
                f32x4 acc[4];
#pragma unroll
                for (int g = 0; g < 4; g++)
                    acc[g] = MFMA16(a1, E1hh[g][1], MFMA16(a0, E1hh[g][0], z4));
                float v[4];
#pragma unroll
                for (int g = 0; g < 4; g++)
                    v[g] = (qb ? acc[g][1] : acc[g][0]) + xt[g];
                float iv = sig2(v[0]), fv = sig2(v[1]);
                float gv = fmaf(2.0f, sig2(v[2]), -1.0f), ov = sig2(v[3]);
                c1 = fv * c1 + iv * gv;
                if (quad < 2) h1l[w][quad][u16] = (f16)(ov * tanh2(c1));
                const int tn = (tau + 1 < 1024) ? tau + 1 : 1023;
                xnq = *(const f32x4*)&xst[tn][qb * 4];
            }
        } else {
            if (tau > 0) {                   // L2: h2(tau-1) = f(h1(tau-1), h2(tau-2))
                const f16* h1p = h1l[w ^ 1][ab];
                const f16* h2p = h2l[w ^ 1][ab];
                f16x8 a0 = *(const f16x8*)(h1p + quad * 8);
                f16x8 a1 = *(const f16x8*)(h1p + 32 + quad * 8);
                f16x8 b0 = *(const f16x8*)(h2p + quad * 8);
                f16x8 b1 = *(const f16x8*)(h2p + 32 + quad * 8);
                f32x4 accA[4], accB[4];
#pragma unroll
                for (int g = 0; g < 4; g++) {
                    accA[g] = MFMA16(a1, E2ih[g][1], MFMA16(a0, E2ih[g][0], bs2[g]));
                    accB[g] = MFMA16(b1, E2hh[g][1], MFMA16(b0, E2hh[g][0], z4));
                }
                float v[4];
#pragma unroll
                for (int g = 0; g < 4; g++)
                    v[g] = (qb ? accA[g][1] : accA[g][0]) +
                           (qb ? accB[g][1] : accB[g][0]);
                float iv = sig2(v[0]), fv = sig2(v[1]);
                float gv = fmaf(2.0f, sig2(v[2]), -1.0f), ov = sig2(v[3]);
                c2 = fv * c2 + iv * gv;
                if (quad < 2) h2l[w][quad][u16] = (f16)(ov * tanh2(c2));
            }
        }
        __syncthreads();
        if (!isB) xq = xnq;
    }
    // encoder final: h2(1023) in h2l[0]; c2 in B registers

    // ---------------- decoder weights (ALL waves load BOTH cells) -----------
    f16x8 D1hh[4][2], W2s[4][2];
    float dxw[4][3], db1[4];
    f32x4 db2s[4];
#pragma unroll
    for (int g = 0; g < 4; g++) {
        const float s = (g == 2) ? (-2.0f * LOG2E) : (-LOG2E);
        const int n = g * 64 + u16;
#pragma unroll
        for (int c = 0; c < 2; c++) {
            const int k0 = c * 32 + quad * 8;
            D1hh[g][c] = ldfrag(d1hh, n, k0, s);
            const float* pa = d2ih + (size_t)n * 64 + k0;
            const float* pb = d2hh + (size_t)n * 64 + k0;
            f16x8 r;
#pragma unroll
            for (int j = 0; j < 8; j++) r[j] = (f16)(s * (pa[j] + pb[j]));
            W2s[g][c] = r;
        }
        dxw[g][0] = s * d1ih[n * 3 + 0];
        dxw[g][1] = s * d1ih[n * 3 + 1];
        dxw[g][2] = s * d1ih[n * 3 + 2];
        db1[g] = s * d1b[n];
        float bv = s * d2b[n];
        db2s[g] = (f32x4){bv, bv, bv, bv};
    }
    // seed: encoder c2 -> every wave's registers (one LDS round-trip total)
    if (isB && quad < 2) c2seed[quad][u16] = c2;
    // FC: register B-fragments of fcW^T (waves 6-7); B[k][n]=fcW[n][k], n=c15
    f16x8 FW0 = {}, FW1 = {};
    float fb = 0.f;
    if (wv >= 6 && c15 < 3) {
#pragma unroll
        for (int j = 0; j < 8; j++) {
            FW0[j] = (f16)fcW[c15 * 64 + quad * 8 + j];
            FW1[j] = (f16)fcW[c15 * 64 + 32 + quad * 8 + j];
        }
        fb = fcb[c15];
    }
    __syncthreads();

    float c2r = c2seed[qb][u16];             // decoder carry c (registers, all waves)
    float c1r = 0.f;

    // trg prefetch registers (all waves)
    f32x4 tq = *(const f32x4*)&tst[0][qb * 4], tnq = z4;

    // ---------------- decoder: 511 steps, 2 barriers each -------------------
    // ALL waves compute both cells (A/B redundant copies); c stays in regs.
#pragma unroll 1
    for (int t = 0; t < 511; t++) {
        const int r = t & 1, w = r ^ 1;
        {
            // ---- dec1 (all waves) ----
            const f16* hp = h2l[r][ab];
            f16x8 a0 = *(const f16x8*)(hp + quad * 8);
            f16x8 a1 = *(const f16x8*)(hp + 32 + quad * 8);
            float xt[4];
#pragma unroll
            for (int g = 0; g < 4; g++)
                xt[g] = fmaf(dxw[g][0], tq.x,
                        fmaf(dxw[g][1], tq.y, fmaf(dxw[g][2], tq.z, db1[g])));
            f32x4 acc[4];
#pragma unroll
            for (int g = 0; g < 4; g++)
                acc[g] = MFMA16(a1, D1hh[g][1], MFMA16(a0, D1hh[g][0], z4));
            float v[4];
#pragma unroll
            for (int g = 0; g < 4; g++)
                v[g] = (qb ? acc[g][1] : acc[g][0]) + xt[g];
            float iv = sig2(v[0]), fv = sig2(v[1]);
            float gv = fmaf(2.0f, sig2(v[2]), -1.0f), ov = sig2(v[3]);
            c1r = fv * c2r + iv * gv;
            if (wv < 4 && quad < 2) h1l[w][quad][u16] = (f16)(ov * tanh2(c1r));
            const int tn = (t + 1 < 511) ? t + 1 : 510;
            tnq = *(const f32x4*)&tst[tn][qb * 4];
        }
        // ---- batched FC for steps t-16..t-1 (waves 6-7, additive) ----
        if (wv >= 6 && t > 0 && (t & 15) == 0) {
            const int bsel = wv - 6;
            const f16* rp = &ring[bsel][0][0];
            f16x8 fa0 = *(const f16x8*)(rp + c15 * 72 + quad * 8);
            f16x8 fa1 = *(const f16x8*)(rp + c15 * 72 + 32 + quad * 8);
            f32x4 facc = MFMA16(fa1, FW1, MFMA16(fa0, FW0, z4));
            if (c15 < 3) {
                float* ob = out + (((size_t)(2 * bp + bsel) * 512 + (t - 15)) * 3) + c15;
#pragma unroll
                for (int rg = 0; rg < 4; rg++)
                    ob[(quad * 4 + rg) * 3] = facc[rg] + fb;
            }
        }
        __syncthreads();   // B1: h1d visible

        {
            // ---- dec2 (all waves): x = h = h1d ----
            const f16* np = h1l[w][ab];
            f16x8 m0 = *(const f16x8*)(np + quad * 8);
            f16x8 m1 = *(const f16x8*)(np + 32 + quad * 8);
            f32x4 acc[4];
#pragma unroll
            for (int g = 0; g < 4; g++)
                acc[g] = MFMA16(m1, W2s[g][1], MFMA16(m0, W2s[g][0], db2s[g]));
            float v[4];
#pragma unroll
            for (int g = 0; g < 4; g++)
                v[g] = (qb ? acc[g][1] : acc[g][0]);
            float i2 = sig2(v[0]), f2 = sig2(v[1]);
            float g2 = fmaf(2.0f, sig2(v[2]), -1.0f), o2 = sig2(v[3]);
            c2r = f2 * c1r + i2 * g2;
            float hh = o2 * tanh2(c2r);
            if (quad < 2) {
                f16 hf = (f16)hh;
                if (wv < 4) h2l[w][quad][u16] = hf;        // state for next dec1
                else        ring[quad][t & 15][u16] = hf;  // FC history
            }
        }
        __syncthreads();   // B2: hD(t) visible
        tq = tnq;
    }

    // drain: FC for steps 496..510 (ring slots 0..14) -> out rows 497..511
    if (wv >= 6) {
        const int bsel = wv - 6;
        const f16* rp = &ring[bsel][0][0];
        f16x8 fa0 = *(const f16x8*)(rp + c15 * 72 + quad * 8);
        f16x8 fa1 = *(const f16x8*)(rp + c15 * 72 + 32 + quad * 8);
        f32x4 facc = MFMA16(fa1, FW1, MFMA16(fa0, FW0, z4));
        if (c15 < 3) {
            float* ob = out + (((size_t)(2 * bp + bsel) * 512 + 497) * 3) + c15;
#pragma unroll
            for (int rg = 0; rg < 4; rg++) {
                int step = quad * 4 + rg;
                if (step < 15) ob[step * 3] = facc[rg] + fb;
            }
        }
    }
}

extern "C" void kernel_launch(void* const* d_in, const int* in_sizes, int n_in,
                              void* d_out, int out_size, void* d_ws, size_t ws_size,
                              hipStream_t stream)
{
    const float* src   = (const float*)d_in[0];
    const float* trg   = (const float*)d_in[1];
    const float* e1ih  = (const float*)d_in[2];
    const float* e1hh  = (const float*)d_in[3];
    const float* e1b   = (const float*)d_in[4];
    const float* e2ih  = (const float*)d_in[5];
    const float* e2hh  = (const float*)d_in[6];
    const float* e2b   = (const float*)d_in[7];
    const float* dd1ih = (const float*)d_in[8];
    const float* dd1hh = (const float*)d_in[9];
    const float* dd1b  = (const float*)d_in[10];
    const float* dd2ih = (const float*)d_in[11];
    const float* dd2hh = (const float*)d_in[12];
    const float* dd2b  = (const float*)d_in[13];
    const float* fcW   = (const float*)d_in[14];
    const float* fcb   = (const float*)d_in[15];
    float* out = (float*)d_out;

    // outputs[:, 0, :] stays 0; decoder fills t >= 1
    hipMemsetAsync(d_out, 0, (size_t)out_size * sizeof(float), stream);

    seq2seq_kernel<<<256, 512, 0, stream>>>(src, trg,
                                            e1ih, e1hh, e1b, e2ih, e2hh, e2b,
                                            dd1ih, dd1hh, dd1b, dd2ih, dd2hh, dd2b,
                                            fcW, fcb, out);
}

// Round 16
// 833.150 us; speedup vs baseline: 1.2658x; 1.1174x over previous
//
#include <hip/hip_runtime.h>
#include <math.h>

typedef _Float16 f16;
typedef _Float16 f16x8 __attribute__((ext_vector_type(8)));
typedef float    f32x4 __attribute__((ext_vector_type(4)));

#define MFMA16(A, B, C) __builtin_amdgcn_mfma_f32_16x16x32_f16((A), (B), (C), 0, 0, 0)
#define LOG2E 1.44269504088896f

// Weights/biases pre-scaled by -log2e (sigmoid) or -2*log2e (g gate):
// sigma(z) = rcp(1 + 2^acc) with a bare v_exp_f32.
__device__ __forceinline__ float sig2(float a) {
    return __builtin_amdgcn_rcpf(1.0f + __builtin_amdgcn_exp2f(a));
}
__device__ __forceinline__ float tanh2(float c) {
    return fmaf(2.0f, sig2(c * (-2.0f * LOG2E)), -1.0f);
}

__device__ __forceinline__ f16x8 ldfrag(const float* __restrict__ W, int n, int k0, float s) {
    const float* p = W + (size_t)n * 64 + k0;
    f16x8 r;
#pragma unroll
    for (int j = 0; j < 8; j++) r[j] = (f16)(s * p[j]);
    return r;
}

// One block per BATCH PAIR; 512 threads = 8 waves, layer-specialized:
// waves 0-3 ("A") = encoder L1 / decoder dec1; waves 4-7 ("B") = encoder L2 /
// decoder dec2. FC head: h2 history ring (16 steps) + 2 MFMAs on waves 6-7
// every 16 steps (replaces per-step shuffle chains on the shared LDS pipe).
// M=2 MFMA rows: batch = row&1 -> C reg0=batch0, reg1=batch1;
// quads (0,2)=b0, (1,3)=b1. Chained K-half MFMAs (r9 form).
__global__ __launch_bounds__(512, 2)
void seq2seq_kernel(const float* __restrict__ src, const float* __restrict__ trg,
                    const float* __restrict__ e1ih, const float* __restrict__ e1hh,
                    const float* __restrict__ e1b,
                    const float* __restrict__ e2ih, const float* __restrict__ e2hh,
                    const float* __restrict__ e2b,
                    const float* __restrict__ d1ih, const float* __restrict__ d1hh,
                    const float* __restrict__ d1b,
                    const float* __restrict__ d2ih, const float* __restrict__ d2hh,
                    const float* __restrict__ d2b,
                    const float* __restrict__ fcW, const float* __restrict__ fcb,
                    float* __restrict__ out)
{
    const int bp   = blockIdx.x;
    const int tid  = threadIdx.x;
    const int wv   = tid >> 6;               // 0..7
    const bool isB = (wv >= 4);
    const int wvg  = wv & 3;
    const int lane = tid & 63;
    const int quad = lane >> 4;
    const int c15  = lane & 15;
    const int u16  = wvg * 16 + c15;
    const int qb   = quad & 1;               // batch this lane's activations
    const int ab   = c15 & 1;                // batch this lane's A-row feeds

    __shared__ __align__(16) float xst[1024][8];   // [t][bat*4+c] src, 32 KB
    __shared__ __align__(16) float tst[512][8];    // trg, 16 KB
    __shared__ __align__(16) f16 h1l[2][2][64];    // [buf][bat][u]
    __shared__ __align__(16) f16 h2l[2][2][64];
    __shared__ float c1buf[2][64];                 // dec1 cell out (A -> B)
    __shared__ float c2buf[2][64];                 // dec2 cell out (B -> A)
    __shared__ __align__(16) f16 ring[2][16][72];  // [bat][step&15][u] h2 history

    // ---- one-time staging of src/trg into LDS ----
    {
        const float* s0 = src + (size_t)(2 * bp) * 3072;
        const float* s1 = s0 + 3072;
        for (int i = tid; i < 3072; i += 512) {
            int t = i / 3, c = i - 3 * t;
            xst[t][c]     = s0[i];
            xst[t][4 + c] = s1[i];
        }
        const float* t0p = trg + (size_t)(2 * bp) * 1536;
        const float* t1p = t0p + 1536;
        for (int i = tid; i < 1536; i += 512) {
            int t = i / 3, c = i - 3 * t;
            tst[t][c]     = t0p[i];
            tst[t][4 + c] = t1p[i];
        }
    }

    // ---- group-specialized encoder weights ----
    f16x8 E1hh[4][2];                        // A only
    f16x8 E2ih[4][2], E2hh[4][2];            // B only
    float xw[4][3], bias1[4];
    f32x4 bs2[4];                            // B: bias2 splat (MFMA C-init)
    if (!isB) {
#pragma unroll
        for (int g = 0; g < 4; g++) {
            const float s = (g == 2) ? (-2.0f * LOG2E) : (-LOG2E);
            const int n = g * 64 + u16;
#pragma unroll
            for (int c = 0; c < 2; c++)
                E1hh[g][c] = ldfrag(e1hh, n, c * 32 + quad * 8, s);
            xw[g][0] = s * e1ih[n * 3 + 0];
            xw[g][1] = s * e1ih[n * 3 + 1];
            xw[g][2] = s * e1ih[n * 3 + 2];
            bias1[g] = s * e1b[n];
        }
    } else {
#pragma unroll
        for (int g = 0; g < 4; g++) {
            const float s = (g == 2) ? (-2.0f * LOG2E) : (-LOG2E);
            const int n = g * 64 + u16;
#pragma unroll
            for (int c = 0; c < 2; c++) {
                E2ih[g][c] = ldfrag(e2ih, n, c * 32 + quad * 8, s);
                E2hh[g][c] = ldfrag(e2hh, n, c * 32 + quad * 8, s);
            }
            float bv = s * e2b[n];
            bs2[g] = (f32x4){bv, bv, bv, bv};
        }
    }

    float c1 = 0.f, c2 = 0.f;                // c1 lives in A, c2 in B
    if (tid < 256) {
        (&h1l[0][0][0])[tid] = (f16)0.f;
        (&h2l[0][0][0])[tid] = (f16)0.f;
    }
    __syncthreads();

    const f32x4 z4 = {0.f, 0.f, 0.f, 0.f};

    // x prefetch registers (A only)
    f32x4 xq = z4, xnq = z4;
    if (!isB) xq = *(const f32x4*)&xst[0][qb * 4];

    // ---------------- encoder: 1025 pipelined ticks, 1 barrier each --------
#pragma unroll 1
    for (int tau = 0; tau <= 1024; tau++) {
        const int w = tau & 1;
        if (!isB) {
            if (tau < 1024) {                // L1: h1(tau) = f(h1(tau-1), x(tau))
                const f16* h1p = h1l[w ^ 1][ab];
                f16x8 a0 = *(const f16x8*)(h1p + quad * 8);
                f16x8 a1 = *(const f16x8*)(h1p + 32 + quad * 8);
                float xt[4];
#pragma unroll
                for (int g = 0; g < 4; g++)
                    xt[g] = fmaf(xw[g][0], xq.x,
                            fmaf(xw[g][1], xq.y, fmaf(xw[g][2], xq.z, bias1[g])));
                f32x4 acc[4];
#pragma unroll
                for (int g = 0; g < 4; g++)
                    acc[g] = MFMA16(a1, E1hh[g][1], MFMA16(a0, E1hh[g][0], z4));
                float v[4];
#pragma unroll
                for (int g = 0; g < 4; g++)
                    v[g] = (qb ? acc[g][1] : acc[g][0]) + xt[g];
                float iv = sig2(v[0]), fv = sig2(v[1]);
                float gv = fmaf(2.0f, sig2(v[2]), -1.0f), ov = sig2(v[3]);
                c1 = fv * c1 + iv * gv;
                if (quad < 2) h1l[w][quad][u16] = (f16)(ov * tanh2(c1));
                // prefetch next x (read-only region; off the post-barrier burst)
                const int tn = (tau + 1 < 1024) ? tau + 1 : 1023;
                xnq = *(const f32x4*)&xst[tn][qb * 4];
            }
        } else {
            if (tau > 0) {                   // L2: h2(tau-1) = f(h1(tau-1), h2(tau-2))
                const f16* h1p = h1l[w ^ 1][ab];
                const f16* h2p = h2l[w ^ 1][ab];
                f16x8 a0 = *(const f16x8*)(h1p + quad * 8);
                f16x8 a1 = *(const f16x8*)(h1p + 32 + quad * 8);
                f16x8 b0 = *(const f16x8*)(h2p + quad * 8);
                f16x8 b1 = *(const f16x8*)(h2p + 32 + quad * 8);
                f32x4 accA[4], accB[4];      // two 2-deep chains, bias in C-init
#pragma unroll
                for (int g = 0; g < 4; g++) {
                    accA[g] = MFMA16(a1, E2ih[g][1], MFMA16(a0, E2ih[g][0], bs2[g]));
                    accB[g] = MFMA16(b1, E2hh[g][1], MFMA16(b0, E2hh[g][0], z4));
                }
                float v[4];
#pragma unroll
                for (int g = 0; g < 4; g++)
                    v[g] = (qb ? accA[g][1] : accA[g][0]) +
                           (qb ? accB[g][1] : accB[g][0]);
                float iv = sig2(v[0]), fv = sig2(v[1]);
                float gv = fmaf(2.0f, sig2(v[2]), -1.0f), ov = sig2(v[3]);
                c2 = fv * c2 + iv * gv;
                if (quad < 2) h2l[w][quad][u16] = (f16)(ov * tanh2(c2));
            }
        }
        __syncthreads();
        if (!isB) xq = xnq;
    }
    // h2(1023) in h2l[0]; c2 in B registers

    // ---------------- decoder weights (group-specialized) -------------------
    f16x8 D1hh[4][2];                        // A
    f16x8 W2s[4][2];                         // B
    float dxw[4][3], db1[4];
    f32x4 db2s[4];                           // B: dec2 bias splat (C-init)
    if (!isB) {
#pragma unroll
        for (int g = 0; g < 4; g++) {
            const float s = (g == 2) ? (-2.0f * LOG2E) : (-LOG2E);
            const int n = g * 64 + u16;
#pragma unroll
            for (int c = 0; c < 2; c++)
                D1hh[g][c] = ldfrag(d1hh, n, c * 32 + quad * 8, s);
            dxw[g][0] = s * d1ih[n * 3 + 0];
            dxw[g][1] = s * d1ih[n * 3 + 1];
            dxw[g][2] = s * d1ih[n * 3 + 2];
            db1[g] = s * d1b[n];
        }
    } else {
#pragma unroll
        for (int g = 0; g < 4; g++) {
            const float s = (g == 2) ? (-2.0f * LOG2E) : (-LOG2E);
            const int n = g * 64 + u16;
#pragma unroll
            for (int c = 0; c < 2; c++) {
                const int k0 = c * 32 + quad * 8;
                const float* pa = d2ih + (size_t)n * 64 + k0;
                const float* pb = d2hh + (size_t)n * 64 + k0;
                f16x8 r;
#pragma unroll
                for (int j = 0; j < 8; j++) r[j] = (f16)(s * (pa[j] + pb[j]));
                W2s[g][c] = r;
            }
            float bv = s * d2b[n];
            db2s[g] = (f32x4){bv, bv, bv, bv};
        }
        // seed c2buf with encoder final c2 (A reads it at t=0)
        if (quad < 2) c2buf[quad][u16] = c2;
    }
    // FC: register B-fragments of fcW^T (waves 6-7), B[k][n]=fcW[n][k], n=c15
    f16x8 FW0 = {}, FW1 = {};
    float fb = 0.f;
    if (wv >= 6 && c15 < 3) {
#pragma unroll
        for (int j = 0; j < 8; j++) {
            FW0[j] = (f16)fcW[c15 * 64 + quad * 8 + j];
            FW1[j] = (f16)fcW[c15 * 64 + 32 + quad * 8 + j];
        }
        fb = fcb[c15];
    }
    __syncthreads();

    // trg prefetch registers (A only)
    f32x4 tq = z4, tnq = z4;
    if (!isB) tq = *(const f32x4*)&tst[0][qb * 4];

    // ---------------- decoder: 511 steps, 2 barriers each -------------------
#pragma unroll 1
    for (int t = 0; t < 511; t++) {
        const int r = t & 1, w = r ^ 1;
        if (!isB) {
            // ---- dec1 (waves 0-3) ----
            const f16* hp = h2l[r][ab];
            f16x8 a0 = *(const f16x8*)(hp + quad * 8);
            f16x8 a1 = *(const f16x8*)(hp + 32 + quad * 8);
            float cdin = c2buf[qb][u16];
            float xt[4];
#pragma unroll
            for (int g = 0; g < 4; g++)
                xt[g] = fmaf(dxw[g][0], tq.x,
                        fmaf(dxw[g][1], tq.y, fmaf(dxw[g][2], tq.z, db1[g])));
            f32x4 acc[4];
#pragma unroll
            for (int g = 0; g < 4; g++)
                acc[g] = MFMA16(a1, D1hh[g][1], MFMA16(a0, D1hh[g][0], z4));
            float v[4];
#pragma unroll
            for (int g = 0; g < 4; g++)
                v[g] = (qb ? acc[g][1] : acc[g][0]) + xt[g];
            float iv = sig2(v[0]), fv = sig2(v[1]);
            float gv = fmaf(2.0f, sig2(v[2]), -1.0f), ov = sig2(v[3]);
            float c1d = fv * cdin + iv * gv;
            if (quad < 2) {
                h1l[w][quad][u16] = (f16)(ov * tanh2(c1d));
                c1buf[quad][u16]  = c1d;
            }
            const int tn = (t + 1 < 511) ? t + 1 : 510;
            tnq = *(const f32x4*)&tst[tn][qb * 4];
        } else if (wv >= 6 && t > 0 && (t & 15) == 0) {
            // ---- batched FC for steps t-16..t-1 (2 MFMAs), overlapped ----
            const int bsel = wv - 6;
            const f16* rp = &ring[bsel][0][0];
            f16x8 fa0 = *(const f16x8*)(rp + c15 * 72 + quad * 8);
            f16x8 fa1 = *(const f16x8*)(rp + c15 * 72 + 32 + quad * 8);
            f32x4 acc = MFMA16(fa1, FW1, MFMA16(fa0, FW0, z4));
            if (c15 < 3) {
                float* ob = out + (((size_t)(2 * bp + bsel) * 512 + (t - 15)) * 3) + c15;
#pragma unroll
                for (int rg = 0; rg < 4; rg++)
                    ob[(quad * 4 + rg) * 3] = acc[rg] + fb;
            }
        }
        __syncthreads();   // B1: h1d, c1d visible
        if (!isB) tq = tnq;

        if (isB) {
            // ---- dec2 (waves 4-7): x = h = h1d ----
            const f16* np = h1l[w][ab];
            f16x8 m0 = *(const f16x8*)(np + quad * 8);
            f16x8 m1 = *(const f16x8*)(np + 32 + quad * 8);
            float c1in = c1buf[qb][u16];
            f32x4 acc[4];
#pragma unroll
            for (int g = 0; g < 4; g++)
                acc[g] = MFMA16(m1, W2s[g][1], MFMA16(m0, W2s[g][0], db2s[g]));
            float v[4];
#pragma unroll
            for (int g = 0; g < 4; g++)
                v[g] = (qb ? acc[g][1] : acc[g][0]);
            float i2 = sig2(v[0]), f2 = sig2(v[1]);
            float g2 = fmaf(2.0f, sig2(v[2]), -1.0f), o2 = sig2(v[3]);
            float c2d = f2 * c1in + i2 * g2;
            if (quad < 2) {
                f16 hh = (f16)(o2 * tanh2(c2d));
                h2l[w][quad][u16] = hh;
                c2buf[quad][u16]  = c2d;
                ring[quad][t & 15][u16] = hh;   // FC history
            }
        }
        __syncthreads();   // B2: hD(t), c2d visible
    }

    // drain: FC for steps 496..510 (ring slots 0..14) -> out rows 497..511
    if (wv >= 6) {
        const int bsel = wv - 6;
        const f16* rp = &ring[bsel][0][0];
        f16x8 fa0 = *(const f16x8*)(rp + c15 * 72 + quad * 8);
        f16x8 fa1 = *(const f16x8*)(rp + c15 * 72 + 32 + quad * 8);
        f32x4 acc = MFMA16(fa1, FW1, MFMA16(fa0, FW0, z4));
        if (c15 < 3) {
            float* ob = out + (((size_t)(2 * bp + bsel) * 512 + 497) * 3) + c15;
#pragma unroll
            for (int rg = 0; rg < 4; rg++) {
                int step = quad * 4 + rg;
                if (step < 15) ob[step * 3] = acc[rg] + fb;
            }
        }
    }
}

extern "C" void kernel_launch(void* const* d_in, const int* in_sizes, int n_in,
                              void* d_out, int out_size, void* d_ws, size_t ws_size,
                              hipStream_t stream)
{
    const float* src   = (const float*)d_in[0];
    const float* trg   = (const float*)d_in[1];
    const float* e1ih  = (const float*)d_in[2];
    const float* e1hh  = (const float*)d_in[3];
    const float* e1b   = (const float*)d_in[4];
    const float* e2ih  = (const float*)d_in[5];
    const float* e2hh  = (const float*)d_in[6];
    const float* e2b   = (const float*)d_in[7];
    const float* dd1ih = (const float*)d_in[8];
    const float* dd1hh = (const float*)d_in[9];
    const float* dd1b  = (const float*)d_in[10];
    const float* dd2ih = (const float*)d_in[11];
    const float* dd2hh = (const float*)d_in[12];
    const float* dd2b  = (const float*)d_in[13];
    const float* fcW   = (const float*)d_in[14];
    const float* fcb   = (const float*)d_in[15];
    float* out = (float*)d_out;

    // outputs[:, 0, :] stays 0; decoder fills t >= 1
    hipMemsetAsync(d_out, 0, (size_t)out_size * sizeof(float), stream);

    seq2seq_kernel<<<256, 512, 0, stream>>>(src, trg,
                                            e1ih, e1hh, e1b, e2ih, e2hh, e2b,
                                            dd1ih, dd1hh, dd1b, dd2ih, dd2hh, dd2b,
                                            fcW, fcb, out);
}